// Round 10
// baseline (768.577 us; speedup 1.0000x reference)
//
#include <hip/hip_runtime.h>
#include <hip/hip_bf16.h>
#include <math.h>

// Problem constants
#define B 32
#define N 128
#define BT (B*N)          // 4096
#define WD 100
#define UD 25
#define D 125             // LSTM hidden per direction
#define G4 (4*D)          // 500 gates
#define H2 (2*D)          // 250
#define HID 100
#define L 50

// Fast, overflow-safe activations on v_exp_f32
__device__ __forceinline__ float fast_tanh(float x) {
    float e = __expf(2.0f * x);
    return 1.0f - 2.0f / (e + 1.0f);
}
__device__ __forceinline__ float fast_sigmoid(float x) {
    return 1.0f / (1.0f + __expf(-x));
}
__device__ __forceinline__ float bcast_lane(float v, int k) {
    return __builtin_bit_cast(float, __builtin_amdgcn_readlane(__builtin_bit_cast(int, v), k));
}

// 64-way macro repetition
#define REP64(X) \
 X(0) X(1) X(2) X(3) X(4) X(5) X(6) X(7) X(8) X(9) \
 X(10) X(11) X(12) X(13) X(14) X(15) X(16) X(17) X(18) X(19) \
 X(20) X(21) X(22) X(23) X(24) X(25) X(26) X(27) X(28) X(29) \
 X(30) X(31) X(32) X(33) X(34) X(35) X(36) X(37) X(38) X(39) \
 X(40) X(41) X(42) X(43) X(44) X(45) X(46) X(47) X(48) X(49) \
 X(50) X(51) X(52) X(53) X(54) X(55) X(56) X(57) X(58) X(59) \
 X(60) X(61) X(62) X(63)

// ---------------------------------------------------------------------------
// K0a: combined-bias setup (b_l0[1000], b_l1[1000], b_s3[300])
// ---------------------------------------------------------------------------
__global__ void bias_setup(const float* __restrict__ l0f_b, const float* __restrict__ l0b_b,
                           const float* __restrict__ l1f_b, const float* __restrict__ l1b_b,
                           const float* __restrict__ eh_b, const float* __restrict__ em_b,
                           const float* __restrict__ lm_b,
                           float* __restrict__ b_l0, float* __restrict__ b_l1,
                           float* __restrict__ b_s3) {
    int t = blockIdx.x * blockDim.x + threadIdx.x;
    if (t < 500)        b_l0[t] = l0f_b[t];
    else if (t < 1000)  b_l0[t] = l0b_b[t-500];
    else if (t < 1500)  b_l1[t-1000] = l1f_b[t-1000];
    else if (t < 2000)  b_l1[t-1000] = l1b_b[t-1500];
    else if (t < 2100)  b_s3[t-2000] = eh_b[t-2000];
    else if (t < 2200)  b_s3[t-2000] = em_b[t-2100];
    else if (t < 2300)  b_s3[t-2000] = lm_b[t-2200];
}

// K0c: zero the pad rows (125..128) of the 4 WhT buffers
__global__ void pad_zero(float* __restrict__ w0, float* __restrict__ w1,
                         float* __restrict__ w2, float* __restrict__ w3) {
    int t = blockIdx.x * blockDim.x + threadIdx.x;   // 4 * 1516 = 6064 elems
    int m = t / 1516, e = t % 1516;
    float* p = (m == 0) ? w0 : (m == 1) ? w1 : (m == 2) ? w2 : w3;
    p[125*500 + e] = 0.0f;                           // covers 125*500 .. 128*500+16
}

// ---------------------------------------------------------------------------
// K0b: fused LDS-tiled transpose. out[k*ldo + coff + n] = in[n*C + k].
// ---------------------------------------------------------------------------
struct TJob { const float* src; float* dst; int R, C, ldo, coff, tile0, tiles_x; };
struct TArgs { TJob j[12]; };

__global__ __launch_bounds__(256)
void transpose_fused(TArgs a) {
    int bid = blockIdx.x;
    int ji = 0;
    #pragma unroll
    for (int i = 1; i < 12; i++) if (bid >= a.j[i].tile0) ji = i;
    TJob jb = a.j[ji];
    int t = bid - jb.tile0;
    int tx = t % jb.tiles_x;        // tile along C (k)
    int ty = t / jb.tiles_x;        // tile along R (n)
    __shared__ float tile[32][33];
    int k0 = tx*32, n0 = ty*32;
    #pragma unroll
    for (int dy = 0; dy < 32; dy += 8) {
        int n = n0 + threadIdx.y + dy;
        int k = k0 + threadIdx.x;
        if (n < jb.R && k < jb.C)
            tile[threadIdx.y+dy][threadIdx.x] = jb.src[(size_t)n*jb.C + k];
    }
    __syncthreads();
    #pragma unroll
    for (int dy = 0; dy < 32; dy += 8) {
        int k = k0 + threadIdx.y + dy;
        int n = n0 + threadIdx.x;
        if (k < jb.C && n < jb.R)
            jb.dst[(size_t)k*jb.ldo + jb.coff + n] = tile[threadIdx.x][threadIdx.y+dy];
    }
}

// ---------------------------------------------------------------------------
// K1: embedding gather
// ---------------------------------------------------------------------------
__global__ void embed_kernel(const int* __restrict__ wids, const int* __restrict__ uids,
                             const float* __restrict__ wl, const float* __restrict__ tl,
                             float* __restrict__ words) {
    int bt = blockIdx.x;
    int t = threadIdx.x;           // 128 threads
    int wid = wids[bt];
    int uid = uids[bt];
    if (t < WD)       words[bt*D + t] = wl[wid*WD + t];
    else if (t < D)   words[bt*D + t] = tl[uid*UD + (t - WD)];
}

// ---------------------------------------------------------------------------
// K2: projection GEMM, transposed weights, CPT columns per thread,
//     software-pipelined WT loads (prefetch next k-group).
// ---------------------------------------------------------------------------
#define MT 16
template<int CPT>
__global__ __launch_bounds__(512)
void proj_t(const float* __restrict__ x, const float* __restrict__ WT,
            const float* __restrict__ bias, float* __restrict__ out,
            int Ncols, int K, int ldx, const int* __restrict__ gather_idx) {
    __shared__ float xs[250 * 17 + 16];   // xs[k*17 + r]
    int m0 = blockIdx.x * MT;
    for (int e = threadIdx.x; e < MT * K; e += blockDim.x) {
        int r = e / K, k = e - r * K;
        int m = m0 + r;
        int row = m;
        if (gather_idx) {
            int bb = m >> 7, np = m & 127;
            row = (bb << 7) + (np == 0 ? 0 : gather_idx[m]);
        }
        xs[k*17 + r] = x[(size_t)row*ldx + k];
    }
    __syncthreads();
    int n0 = threadIdx.x;
    int lane = threadIdx.x & 63;
    int bd = blockDim.x;
    float acc[CPT][MT];
    int ncl[CPT];
    #pragma unroll
    for (int j = 0; j < CPT; j++) {
        int n = n0 + j*bd;
        ncl[j] = (n < Ncols) ? n : (Ncols - 1);
        #pragma unroll
        for (int r = 0; r < MT; r++) acc[j][r] = 0.0f;
    }
    float wkc[4][CPT];
    #pragma unroll
    for (int q = 0; q < 4; q++)
        #pragma unroll
        for (int j = 0; j < CPT; j++)
            wkc[q][j] = WT[(size_t)q*Ncols + ncl[j]];     // K >= 4 always
    int k0 = 0;
    for (; k0 + 8 <= K; k0 += 4) {
        float xv = xs[(k0 + (lane >> 4))*17 + (lane & 15)];
        float wkn[4][CPT];
        #pragma unroll
        for (int q = 0; q < 4; q++)
            #pragma unroll
            for (int j = 0; j < CPT; j++)
                wkn[q][j] = WT[(size_t)(k0 + 4 + q)*Ncols + ncl[j]];
        #pragma unroll
        for (int q = 0; q < 4; q++) {
            #pragma unroll
            for (int r = 0; r < 16; r++) {
                float hv = bcast_lane(xv, q*16 + r);
                #pragma unroll
                for (int j = 0; j < CPT; j++)
                    acc[j][r] = fmaf(wkc[q][j], hv, acc[j][r]);
            }
        }
        #pragma unroll
        for (int q = 0; q < 4; q++)
            #pragma unroll
            for (int j = 0; j < CPT; j++)
                wkc[q][j] = wkn[q][j];
    }
    { // last full group
        float xv = xs[(k0 + (lane >> 4))*17 + (lane & 15)];
        #pragma unroll
        for (int q = 0; q < 4; q++) {
            #pragma unroll
            for (int r = 0; r < 16; r++) {
                float hv = bcast_lane(xv, q*16 + r);
                #pragma unroll
                for (int j = 0; j < CPT; j++)
                    acc[j][r] = fmaf(wkc[q][j], hv, acc[j][r]);
            }
        }
        k0 += 4;
    }
    for (; k0 < K; k0++) {                 // tail (K=125 -> 1, K=250 -> 2)
        float xv = xs[k0*17 + (lane & 15)];
        float wk[CPT];
        #pragma unroll
        for (int j = 0; j < CPT; j++) wk[j] = WT[(size_t)k0*Ncols + ncl[j]];
        #pragma unroll
        for (int r = 0; r < 16; r++) {
            float hv = bcast_lane(xv, r);
            #pragma unroll
            for (int j = 0; j < CPT; j++)
                acc[j][r] = fmaf(wk[j], hv, acc[j][r]);
        }
    }
    #pragma unroll
    for (int j = 0; j < CPT; j++) {
        int n = n0 + j*bd;
        if (n < Ncols) {
            float bb = bias[n];
            #pragma unroll
            for (int r = 0; r < MT; r++) out[(size_t)(m0 + r)*Ncols + n] = acc[j][r] + bb;
        }
    }
}

// ---------------------------------------------------------------------------
// K3: LSTM scan, k-split. 1024 threads per (b,dir): thread = (gate g, k-half).
//     Weights parked ONCE in explicit physical AGPRs a0..a63 (RA cannot spill
//     or remat physical regs referenced by asm — rounds 2-9 showed every
//     source-level trick fails: VGPR 76/76/76/88/52/52/52). Loop fetches each
//     weight with a volatile v_accvgpr_read (VALU, no memory traffic).
// ---------------------------------------------------------------------------
__global__ __launch_bounds__(1024)
void lstm_scan(const float* __restrict__ xgc,
               const float* __restrict__ WhTf, const float* __restrict__ WhTb,
               float* __restrict__ out) {
    int dir = blockIdx.x & 1;
    int b = blockIdx.x >> 1;
    const float* WhT = dir ? WhTb : WhTf;   // [128][500], zero-padded rows 125..127
    int off = dir ? D : 0;
    int t = threadIdx.x;
    int g = t & 511;
    int half = t >> 9;
    int lane = t & 63;
    int kbase = half << 6;                  // 0 or 64

    __shared__ float hbuf[128];
    __shared__ float pbuf[1024];

    // park Whh[kbase+i][g] in physical AGPR a<i>  (buffer is 64,016 floats;
    // max addr (127*500+511)=64,011 in-bounds; g in [500,512) reads garbage
    // that is never consumed downstream)
#define PARKW(i) { float wtmp = WhT[(size_t)(kbase + (i)) * 500 + g]; \
    asm volatile("v_accvgpr_write_b32 a" #i ", %0" :: "v"(wtmp) : "a" #i); }
    REP64(PARKW)
#undef PARKW

    float c = 0.0f;
    if (t < 128) hbuf[t] = 0.0f;
    __syncthreads();

    const float* xb = xgc + (size_t)b * N * 1000 + dir * 500;
    bool xa = (half == 0) && (g < G4);
    float x_next = xa ? xb[(size_t)(dir ? (N-1) : 0) * 1000 + g] : 0.0f;

    for (int ti = 0; ti < N; ti++) {
        int tt = dir ? (N-1-ti) : ti;
        float x_cur = x_next;
        float xn = 0.0f;
        if (xa && ti + 1 < N)
            xn = xb[(size_t)(dir ? (tt-1) : (tt+1)) * 1000 + g];
        float hseg = hbuf[kbase + lane];     // lane i holds h[kbase+i]
        float a4[4];
        a4[0] = x_cur; a4[1] = 0.0f; a4[2] = 0.0f; a4[3] = 0.0f;
        // volatile read -> exactly one accvgpr_read per use per iteration;
        // fmaf(wt, uniform, acc) -> v_fmac acc, s_h, v_wt
#define FMAW(i) { float wt; \
    asm volatile("v_accvgpr_read_b32 %0, a" #i : "=v"(wt)); \
    a4[(i)&3] = fmaf(wt, bcast_lane(hseg, i), a4[(i)&3]); }
        REP64(FMAW)
#undef FMAW
        x_next = xn;
        pbuf[t] = (a4[0] + a4[1]) + (a4[2] + a4[3]);
        __syncthreads();
        if (t < D) {
            float iv = pbuf[t]       + pbuf[512 + t];
            float fv = pbuf[D+t]     + pbuf[512 + D+t];
            float gv = pbuf[2*D+t]   + pbuf[512 + 2*D+t];
            float ov = pbuf[3*D+t]   + pbuf[512 + 3*D+t];
            float si = fast_sigmoid(iv);
            float sf = fast_sigmoid(fv);
            float so = fast_sigmoid(ov);
            c = sf * c + si * fast_tanh(gv);
            float h = so * fast_tanh(c);
            hbuf[t] = h;
            out[(size_t)(b*N + tt)*H2 + off + t] = h;
        }
        __syncthreads();
    }
}

// ---------------------------------------------------------------------------
// K4: arc scores + margin + argmax. Block per (b, 4-i tile); 128 threads (j).
// ---------------------------------------------------------------------------
#define ITILE 4
__global__ __launch_bounds__(128)
void arc_kernel(const float* __restrict__ s3,
                const float* __restrict__ esW, const float* __restrict__ esb,
                const int* __restrict__ ta,
                float* __restrict__ arc_out, float* __restrict__ tree_out) {
    int blk = blockIdx.x;             // b*32 + it
    int b = blk >> 5, it = blk & 31;
    int j = threadIdx.x;              // 128 threads

    __shared__ float wms[128 * 101];
    __shared__ float whs[ITILE][HID];
    __shared__ float es[HID];
    __shared__ float sv[128];
    __shared__ int   si[128];

    for (int e = j; e < 128 * HID; e += 128) {
        int r = e / HID, h = e - r * HID;
        wms[r*101 + h] = s3[(size_t)(b*N + r)*300 + 100 + h];
    }
    for (int e = j; e < ITILE * HID; e += 128) {
        int ii = e / HID, h = e - ii * HID;
        whs[ii][h] = s3[(size_t)(b*N + it*ITILE + ii)*300 + h];
    }
    if (j < HID) es[j] = esW[j];
    __syncthreads();

    float eb = esb[0];
    const float* wmr = &wms[j * 101];
    for (int ii = 0; ii < ITILE; ii++) {
        int i = it * ITILE + ii;
        int bi = b * N + i;
        float acc = 0.0f;
        for (int h = 0; h < HID; h++)
            acc = fmaf(es[h], fast_tanh(whs[ii][h] + wmr[h]), acc);
        int tai = (i == 0) ? 0 : ta[bi];
        float score = acc + eb + 1.0f - ((j == tai) ? 1.0f : 0.0f);
        arc_out[(size_t)bi*N + j] = score;
        sv[j] = score; si[j] = j;
        __syncthreads();
        for (int s = 64; s; s >>= 1) {
            if (j < s) {
                float ov = sv[j+s]; int oi = si[j+s];
                if (ov > sv[j] || (ov == sv[j] && oi < si[j])) { sv[j] = ov; si[j] = oi; }
            }
            __syncthreads();
        }
        if (j == 0) tree_out[bi] = (float)si[0];
        __syncthreads();
    }
}

// ---------------------------------------------------------------------------
// K5: rel scores + argmax. One block (64 threads) per bt.
// ---------------------------------------------------------------------------
__global__ void rel_kernel(const float* __restrict__ s3, const float* __restrict__ rh,
                           const float* __restrict__ lsW, const float* __restrict__ lsb,
                           float* __restrict__ rel_out, float* __restrict__ pred_out) {
    int bt = blockIdx.x;
    int t = threadIdx.x;          // 64 threads

    __shared__ float tv[HID];
    __shared__ float sv[64];
    __shared__ int   si[64];

    for (int h = t; h < HID; h += 64)
        tv[h] = fast_tanh(s3[(size_t)bt*300 + 200 + h] + rh[(size_t)bt*HID + h]);
    __syncthreads();

    float score = -1e30f;
    if (t < L) {
        float acc = 0.0f;
        const float* wrow = lsW + t*HID;
        for (int h = 0; h < HID; h++) acc = fmaf(wrow[h], tv[h], acc);
        score = acc + lsb[t];
        rel_out[(size_t)bt*L + t] = score;
    }
    sv[t] = score;
    si[t] = t;
    __syncthreads();
    for (int s = 32; s; s >>= 1) {
        if (t < s) {
            float ov = sv[t + s]; int oi = si[t + s];
            if (ov > sv[t] || (ov == sv[t] && oi < si[t])) { sv[t] = ov; si[t] = oi; }
        }
        __syncthreads();
    }
    if (t == 0) pred_out[bt] = (float)si[0];
}

// ---------------------------------------------------------------------------
extern "C" void kernel_launch(void* const* d_in, const int* in_sizes, int n_in,
                              void* d_out, int out_size, void* d_ws, size_t ws_size,
                              hipStream_t stream) {
    const int*   word_ids    = (const int*)  d_in[0];
    const int*   upos_ids    = (const int*)  d_in[1];
    const int*   target_arcs = (const int*)  d_in[2];
    const float* wlookup     = (const float*)d_in[3];
    const float* tlookup     = (const float*)d_in[4];
    const float* l0f_Wih = (const float*)d_in[5];
    const float* l0f_Whh = (const float*)d_in[6];
    const float* l0f_b   = (const float*)d_in[7];
    const float* l0b_Wih = (const float*)d_in[8];
    const float* l0b_Whh = (const float*)d_in[9];
    const float* l0b_b   = (const float*)d_in[10];
    const float* l1f_Wih = (const float*)d_in[11];
    const float* l1f_Whh = (const float*)d_in[12];
    const float* l1f_b   = (const float*)d_in[13];
    const float* l1b_Wih = (const float*)d_in[14];
    const float* l1b_Whh = (const float*)d_in[15];
    const float* l1b_b   = (const float*)d_in[16];
    const float* eh_W = (const float*)d_in[17];
    const float* eh_b = (const float*)d_in[18];
    const float* em_W = (const float*)d_in[19];
    const float* em_b = (const float*)d_in[20];
    const float* es_W = (const float*)d_in[21];
    const float* es_b = (const float*)d_in[22];
    const float* lh_W = (const float*)d_in[23];
    const float* lh_b = (const float*)d_in[24];
    const float* lm_W = (const float*)d_in[25];
    const float* lm_b = (const float*)d_in[26];
    const float* ls_W = (const float*)d_in[27];
    const float* ls_b = (const float*)d_in[28];

    float* out = (float*)d_out;
    float* trees_out = out;                         // 4096
    float* preds_out = out + BT;                    // 4096
    float* arc_out   = out + 2*BT;                  // 524288
    float* rel_out   = out + 2*BT + BT*N;           // 204800

    float* ws = (float*)d_ws;
    float* A       = ws;                    // 4,096,000: xg fused [m][1000]; later s3 [m][300]
    float* words   = ws + 4096000;          //   512,000
    float* C       = ws + 4608000;          // 1,024,000: h0, then ex
    float* WT_l0   = ws + 5632000;          //   125,000  [125][1000]
    float* WT_l1   = ws + 5757000;          //   250,000  [250][1000]
    float* WT_s3   = ws + 6007000;          //    75,000  [250][300]
    float* WT_lh   = ws + 6082000;          //    25,000  [250][100]
    float* WhT_l0f = ws + 6107000;          //    64,016  [128][500]+16 (pad rows zeroed)
    float* WhT_l0b = ws + 6171016;          //    64,016
    float* WhT_l1f = ws + 6235032;          //    64,016
    float* WhT_l1b = ws + 6299048;          //    64,016
    float* b_l0    = ws + 6363064;          //     1,000
    float* b_l1    = ws + 6364064;          //     1,000
    float* b_s3    = ws + 6365064;          //     1,000 (300 used)
    float* rel_head = ws + 6366064;         //   409,600  [m][100]
    // total 6,775,664 floats = 27.1 MB

    // 0. fused biases + pad-row zeroing + fused tiled transpose (12 matrices)
    bias_setup<<<9, 256, 0, stream>>>(l0f_b, l0b_b, l1f_b, l1b_b, eh_b, em_b, lm_b,
                                      b_l0, b_l1, b_s3);
    pad_zero<<<24, 256, 0, stream>>>(WhT_l0f, WhT_l0b, WhT_l1f, WhT_l1b);
    {
        TArgs ta{};
        auto tiles = [](int R, int C_) { return ((C_+31)/32) * ((R+31)/32); };
        struct { const float* s; float* d; int R, C, ldo, coff; } js[12] = {
            { l0f_Wih, WT_l0, 500, 125, 1000, 0 },
            { l0b_Wih, WT_l0, 500, 125, 1000, 500 },
            { l1f_Wih, WT_l1, 500, 250, 1000, 0 },
            { l1b_Wih, WT_l1, 500, 250, 1000, 500 },
            { eh_W, WT_s3, 100, 250, 300, 0 },
            { em_W, WT_s3, 100, 250, 300, 100 },
            { lm_W, WT_s3, 100, 250, 300, 200 },
            { lh_W, WT_lh, 100, 250, 100, 0 },
            { l0f_Whh, WhT_l0f, 500, 125, 500, 0 },
            { l0b_Whh, WhT_l0b, 500, 125, 500, 0 },
            { l1f_Whh, WhT_l1f, 500, 125, 500, 0 },
            { l1b_Whh, WhT_l1b, 500, 125, 500, 0 },
        };
        int t0 = 0;
        for (int i = 0; i < 12; i++) {
            ta.j[i].src = js[i].s;  ta.j[i].dst = js[i].d;
            ta.j[i].R = js[i].R;    ta.j[i].C = js[i].C;
            ta.j[i].ldo = js[i].ldo; ta.j[i].coff = js[i].coff;
            ta.j[i].tile0 = t0;
            ta.j[i].tiles_x = (js[i].C + 31) / 32;
            t0 += tiles(js[i].R, js[i].C);
        }
        transpose_fused<<<t0, dim3(32, 8), 0, stream>>>(ta);
    }

    // 1. embeddings
    embed_kernel<<<BT, 128, 0, stream>>>(word_ids, upos_ids, wlookup, tlookup, words);

    // 2. layer-0 input projections, fused fwd+bwd (K=125, N=1000)
    proj_t<2><<<BT/MT, 512, 0, stream>>>(words, WT_l0, b_l0, A, 1000, D, D, nullptr);

    // 3. layer-0 scan -> h0 (C)
    lstm_scan<<<B*2, 1024, 0, stream>>>(A, WhT_l0f, WhT_l0b, C);

    // 4. layer-1 input projections (K=250, N=1000)
    proj_t<2><<<BT/MT, 512, 0, stream>>>(C, WT_l1, b_l1, A, 1000, H2, H2, nullptr);

    // 5. layer-1 scan -> ex (C, overwrites h0)
    lstm_scan<<<B*2, 1024, 0, stream>>>(A, WhT_l1f, WhT_l1b, C);

    // 6. scorer projections: eh+em+lm fused (N=300) into A; lh gathered (N=100)
    proj_t<2><<<BT/MT, 192, 0, stream>>>(C, WT_s3, b_s3, A, 300, H2, H2, nullptr);
    proj_t<1><<<BT/MT, 128, 0, stream>>>(C, WT_lh, lh_b, rel_head, 100, H2, H2, target_arcs);

    // 7. arc scores + margin + argmax
    arc_kernel<<<BT/ITILE, 128, 0, stream>>>(A, es_W, es_b, target_arcs,
                                             arc_out, trees_out);

    // 8. rel scores + argmax
    rel_kernel<<<BT, 64, 0, stream>>>(A, rel_head, ls_W, ls_b, rel_out, preds_out);
}